// Round 8
// baseline (564.699 us; speedup 1.0000x reference)
//
#include <hip/hip_runtime.h>
#include <math.h>

#define N_NODES 20000
#define N_EDGES 4000
#define IN_DIM 128
#define NUM_HEADS 8
#define ALPHA 0.2f

#define HB_W 64      // u64 words per Hb row (e-bits): 4096 bits
#define HBT_W 320    // u64 words per HbT row (n-bits): 20480 bits
#define KPAD1 20480
#define KPAD2 4096
#define IPAD1 4096   // 16 blocks x 256 rows
#define IPAD2 20224  // 79 blocks x 256 rows
#define SPLITS1 16   // 1280 k each = 10 stages of 128  [R8: was 32; halves P1 traffic,
                     //  identical per-CU stage/barrier count: 512blk@2/CU == 256blk@1/CU]
#define SPLITS2 4    // 1024 k each = 8 stages of 128   [R8: was 8; halves P2 traffic]

typedef float f32x4 __attribute__((ext_vector_type(4)));
typedef __bf16 bf16x8 __attribute__((ext_vector_type(8)));

// ---------- workspace layout (bytes) ----------
// Hb   : u64 [20000][64]   @ 0           10,240,000
// HbT  : u64 [4000][320]   @ 10,240,000  10,240,000
// VtT1 : bf16 [80][20480]  @ 20,480,000   3,276,800
// VtT2 : bf16 [64][4096]   @ 23,756,800     524,288
// expn : f32 [20000][8]    @ 24,281,088     640,000
// Yv   : f32 [20000][64]   @ 24,921,088   5,120,000
// P    : f32 partials      @ 30,041,088  (P1: 16x4096x80=21.0MB / P2: 4x20224x64=20.7MB)

__device__ __forceinline__ unsigned short f2b(float f) {  // fp32 -> bf16 RNE
    unsigned u = __float_as_uint(f);
    return (unsigned short)((u + 0x7FFFu + ((u >> 16) & 1u)) >> 16);
}

// ---- bitpack H: register-only shfl-OR tree; 2 loads in flight per round ----
__global__ void __launch_bounds__(256) k_pack4(const int* __restrict__ H,
                                               unsigned long long* __restrict__ Hb) {
    int wq = threadIdx.x >> 6;
    int lane = threadIdx.x & 63;
    int n = blockIdx.x * 4 + wq;
    const int* hrow = H + (size_t)n * N_EDGES;
    unsigned long long* brow = Hb + (size_t)n * HB_W;
    int g = lane >> 4;
    int sh = 4 * (lane & 15);
    for (int it = 0; it < 16; it += 2) {
        int e0 = it * 256 + lane * 4;
        int e1 = e0 + 256;
        unsigned long long v0 = 0ull, v1 = 0ull;
        if (e0 < N_EDGES) {
            int4 v = *(const int4*)(hrow + e0);
            unsigned nb = (v.x > 0 ? 1u : 0u) | (v.y > 0 ? 2u : 0u) |
                          (v.z > 0 ? 4u : 0u) | (v.w > 0 ? 8u : 0u);
            v0 = (unsigned long long)nb << sh;
        }
        if (e1 < N_EDGES) {
            int4 v = *(const int4*)(hrow + e1);
            unsigned nb = (v.x > 0 ? 1u : 0u) | (v.y > 0 ? 2u : 0u) |
                          (v.z > 0 ? 4u : 0u) | (v.w > 0 ? 8u : 0u);
            v1 = (unsigned long long)nb << sh;
        }
        v0 |= __shfl_xor(v0, 1, 64);  v1 |= __shfl_xor(v1, 1, 64);
        v0 |= __shfl_xor(v0, 2, 64);  v1 |= __shfl_xor(v1, 2, 64);
        v0 |= __shfl_xor(v0, 4, 64);  v1 |= __shfl_xor(v1, 4, 64);
        v0 |= __shfl_xor(v0, 8, 64);  v1 |= __shfl_xor(v1, 8, 64);
        if ((lane & 15) == 0) {
            brow[it * 4 + g] = v0;
            brow[it * 4 + 4 + g] = v1;
        }
    }
}

// ---- ballot bit-transpose: Hb[n][e-word] -> HbT[e][n-word] ----
__global__ void __launch_bounds__(256) k_transB(const unsigned long long* __restrict__ Hb,
                                                unsigned long long* __restrict__ HbT) {
    int wq = threadIdx.x >> 6;
    int lane = threadIdx.x & 63;
    int et = blockIdx.y * 4 + wq;
    if (et >= 63) return;
    int n0 = blockIdx.x * 64;
    int n = n0 + lane;
    unsigned long long w = (n < N_NODES) ? Hb[(size_t)n * HB_W + et] : 0ull;
    unsigned long long out = 0ull;
#pragma unroll
    for (int c = 0; c < 64; c++) {
        unsigned long long b = __ballot((w >> c) & 1ull);
        if (lane == c) out = b;
    }
    int e = et * 64 + lane;
    if (e < N_EDGES) HbT[(size_t)e * HBT_W + blockIdx.x] = out;
}

// ---- fused: Xh = X@W ; s = leaky_relu(Xh.a) ; e = exp(s) (max-shift cancels) ----
// One wave per node: max TLP (5000 blocks). [R5: 320-block fused variant regressed ~60us.]
__global__ void __launch_bounds__(256) k_fused1(const float* __restrict__ X,
                                                const float* __restrict__ W,
                                                const float* __restrict__ att,
                                                float* __restrict__ expn,
                                                float* __restrict__ Yv) {
    int t = blockIdx.x * blockDim.x + threadIdx.x;
    int n = __builtin_amdgcn_readfirstlane(t >> 6);
    int d = t & 63;
    const float* x = X + (size_t)n * IN_DIM;
    float acc = 0.f;
#pragma unroll 8
    for (int k = 0; k < IN_DIM; k++) acc += x[k] * W[k * 64 + d];
    int h = d >> 3, j = d & 7;
    float av = att[h * 16 + j] + att[h * 16 + 8 + j];
    float v = acc * av;
    v += __shfl_xor(v, 1, 64);
    v += __shfl_xor(v, 2, 64);
    v += __shfl_xor(v, 4, 64);
    float s = (v >= 0.f) ? v : ALPHA * v;
    float e = expf(s);
    Yv[(size_t)n * 64 + d] = e * acc;
    if (j == 0) expn[(size_t)n * NUM_HEADS + h] = e;
}

// ---- Yv + expn -> VtT1 bf16 [80][KPAD1] transposed (rows 0-63 Yv^T, 64-71 expn^T, 72-79 zero)
__global__ void __launch_bounds__(256) k_transFE(const float* __restrict__ Yv,
                                                 const float* __restrict__ expn,
                                                 unsigned short* __restrict__ VtT1) {
    __shared__ float tl[64][65];
    int t = threadIdx.x;
    int n0 = blockIdx.x * 64;
    int r = t >> 2, s4 = t & 3;
#pragma unroll
    for (int m = 0; m < 4; m++) {
        int cbase = s4 * 16 + m * 4;
        float4 v = make_float4(0.f, 0.f, 0.f, 0.f);
        if (n0 + r < N_NODES) v = *(const float4*)(Yv + (size_t)(n0 + r) * 64 + cbase);
        tl[r][cbase] = v.x; tl[r][cbase + 1] = v.y; tl[r][cbase + 2] = v.z; tl[r][cbase + 3] = v.w;
    }
    __syncthreads();
    int d = t >> 2;
    unsigned short buf[16];
#pragma unroll
    for (int j = 0; j < 16; j++) buf[j] = f2b(tl[s4 * 16 + j][d]);
    uint4* o = (uint4*)(VtT1 + (size_t)d * KPAD1 + n0 + s4 * 16);
    o[0] = *(uint4*)&buf[0];
    o[1] = *(uint4*)&buf[8];
    int nl = t & 63;
    int rw = t >> 6;
#pragma unroll
    for (int p = 0; p < 4; p++) {
        int row = 64 + rw * 4 + p;
        float v = 0.f;
        if (row < 72 && n0 + nl < N_NODES) v = expn[(size_t)(n0 + nl) * NUM_HEADS + (row - 64)];
        VtT1[(size_t)row * KPAD1 + n0 + nl] = f2b(v);
    }
}

__device__ __forceinline__ bf16x8 expand8(unsigned b) {
    union { uint4 u; bf16x8 v; } cv;
    cv.u.x = ((b & 1u)   ? 0x3F80u : 0u) | ((b & 2u)   ? 0x3F800000u : 0u);
    cv.u.y = ((b & 4u)   ? 0x3F80u : 0u) | ((b & 8u)   ? 0x3F800000u : 0u);
    cv.u.z = ((b & 16u)  ? 0x3F80u : 0u) | ((b & 32u)  ? 0x3F800000u : 0u);
    cv.u.w = ((b & 64u)  ? 0x3F80u : 0u) | ((b & 128u) ? 0x3F800000u : 0u);
    return cv.v;
}
__device__ __forceinline__ bf16x8 ldsread(const unsigned short* p) {
    union { uint4 u; bf16x8 v; } cv;
    cv.u = *(const uint4*)p;
    return cv.v;
}

// ---- bit-mask MFMA GEMM: C[I, NCT*16] = bits[I,K] @ V[K, NCT*16]
// Fragment-order LDS (conflict-free b128 reads/writes). Wave owns 4 row-tiles;
// block = 256 rows; K-split over grid.y -> disjoint fp32 partials (no atomics).
template <int NCT>
__global__ void __launch_bounds__(256) k_mm(const unsigned long long* __restrict__ bits,
                                            int stride, int I,
                                            const unsigned short* __restrict__ Vg,
                                            int Kpad, int kPerSplit,
                                            float* __restrict__ P, int Ipad) {
    __shared__ __align__(16) unsigned short VldsF[NCT * 4 * 64 * 8];
    const int t = threadIdx.x;
    const int l = t & 63;
    const int w = t >> 6;
    const int q = l >> 4;
    const int cl = l & 15;
    const int rowbase = blockIdx.x * 256 + w * 64;
    const int k0 = blockIdx.y * kPerSplit;
    const int nstages = kPerSplit >> 7;

    const unsigned long long* bp[4];
#pragma unroll
    for (int rt = 0; rt < 4; rt++) {
        int r = rowbase + rt * 16 + cl;
        if (r >= I) r = I - 1;
        bp[rt] = bits + (size_t)r * stride;
    }

    f32x4 acc[4][NCT];
#pragma unroll
    for (int rt = 0; rt < 4; rt++)
#pragma unroll
        for (int c = 0; c < NCT; c++) acc[rt][c] = (f32x4){0.f, 0.f, 0.f, 0.f};

    for (int st = 0; st < nstages; st++) {
        int kc = k0 + st * 128;
        __syncthreads();
#pragma unroll
        for (int c = 0; c < NCT; c++) {
            uint4 val = *(const uint4*)(Vg + (size_t)(c * 16 + cl) * Kpad + kc + (w * 4 + q) * 8);
            *(uint4*)&VldsF[(((c * 4 + w) * 64) + l) * 8] = val;
        }
        ulonglong2 wb[4];
#pragma unroll
        for (int rt = 0; rt < 4; rt++) wb[rt] = *(const ulonglong2*)(bp[rt] + (kc >> 6));
        __syncthreads();
#pragma unroll
        for (int kf = 0; kf < 4; kf++) {
            bf16x8 a[4];
#pragma unroll
            for (int rt = 0; rt < 4; rt++) {
                unsigned long long wsel = (kf < 2) ? wb[rt].x : wb[rt].y;
                unsigned byte = (unsigned)(wsel >> ((kf & 1) * 32 + q * 8)) & 0xFFu;
                a[rt] = expand8(byte);
            }
#pragma unroll
            for (int c = 0; c < NCT; c++) {
                bf16x8 bv = ldsread(&VldsF[(((c * 4 + kf) * 64) + l) * 8]);
#pragma unroll
                for (int rt = 0; rt < 4; rt++)
                    acc[rt][c] = __builtin_amdgcn_mfma_f32_16x16x32_bf16(a[rt], bv, acc[rt][c], 0, 0, 0);
            }
        }
    }

    size_t base = (size_t)blockIdx.y * Ipad;
#pragma unroll
    for (int rt = 0; rt < 4; rt++)
#pragma unroll
        for (int c = 0; c < NCT; c++)
#pragma unroll
            for (int r = 0; r < 4; r++)
                P[(base + rowbase + rt * 16 + q * 4 + r) * (NCT * 16) + c * 16 + cl] = acc[rt][c][r];
}

// ---- reduce pass-1 partials, divide, write VtT2 bf16 transposed ----
__global__ void __launch_bounds__(256) k_aggT(const float* __restrict__ P1,
                                              unsigned short* __restrict__ VtT2) {
    __shared__ float tl[64][65];
    int t = threadIdx.x;
    int e0 = blockIdx.x * 64;
    int el = t >> 2, s4 = t & 3;
    int e = e0 + el;
    float num[16];
#pragma unroll
    for (int j = 0; j < 16; j++) num[j] = 0.f;
    float den0 = 0.f, den1 = 0.f;
    for (int sp = 0; sp < SPLITS1; sp++) {
        const float* row = P1 + ((size_t)sp * IPAD1 + e) * 80;
        const float4* r4 = (const float4*)(row + s4 * 16);
        float4 a = r4[0], b = r4[1], c = r4[2], d = r4[3];
        num[0] += a.x;  num[1] += a.y;  num[2] += a.z;  num[3] += a.w;
        num[4] += b.x;  num[5] += b.y;  num[6] += b.z;  num[7] += b.w;
        num[8] += c.x;  num[9] += c.y;  num[10] += c.z; num[11] += c.w;
        num[12] += d.x; num[13] += d.y; num[14] += d.z; num[15] += d.w;
        float2 dn = *(const float2*)(row + 64 + s4 * 2);
        den0 += dn.x; den1 += dn.y;
    }
#pragma unroll
    for (int j = 0; j < 16; j++) {
        float den = (j < 8) ? den0 : den1;
        float v = (e < N_EDGES && den > 0.f) ? num[j] / den : 0.f;
        tl[el][s4 * 16 + j] = v;
    }
    __syncthreads();
    int d = t >> 2;
    unsigned short buf[16];
#pragma unroll
    for (int j = 0; j < 16; j++) buf[j] = f2b(tl[s4 * 16 + j][d]);
    uint4* o = (uint4*)(VtT2 + (size_t)d * KPAD2 + e0 + s4 * 16);
    o[0] = *(uint4*)&buf[0];
    o[1] = *(uint4*)&buf[8];
}

// ---- out = sum of pass-2 partials + bias (float4) ----
__global__ void __launch_bounds__(256) k_final4(const float* __restrict__ P2,
                                                const float* __restrict__ bias,
                                                float* __restrict__ out) {
    int t = blockIdx.x * blockDim.x + threadIdx.x;   // 320000 threads
    int n = t >> 4, c4 = t & 15;
    float4 v = *(const float4*)(bias + c4 * 4);
#pragma unroll
    for (int sp = 0; sp < SPLITS2; sp++) {
        float4 p = *(const float4*)(P2 + ((size_t)sp * IPAD2 + n) * 64 + c4 * 4);
        v.x += p.x; v.y += p.y; v.z += p.z; v.w += p.w;
    }
    *(float4*)(out + (size_t)n * 64 + c4 * 4) = v;
}

extern "C" void kernel_launch(void* const* d_in, const int* in_sizes, int n_in,
                              void* d_out, int out_size, void* d_ws, size_t ws_size,
                              hipStream_t stream) {
    const float* X = (const float*)d_in[0];
    const int* H = (const int*)d_in[1];
    const float* W = (const float*)d_in[2];
    const float* att = (const float*)d_in[3];
    const float* bias = (const float*)d_in[4];
    float* out = (float*)d_out;

    char* ws = (char*)d_ws;
    unsigned long long* Hb  = (unsigned long long*)(ws + 0);
    unsigned long long* HbT = (unsigned long long*)(ws + 10240000);
    unsigned short* VtT1 = (unsigned short*)(ws + 20480000);
    unsigned short* VtT2 = (unsigned short*)(ws + 23756800);
    float* expn = (float*)(ws + 24281088);
    float* Yv   = (float*)(ws + 24921088);
    float* P    = (float*)(ws + 30041088);

    k_pack4<<<5000, 256, 0, stream>>>(H, Hb);
    k_transB<<<dim3(313, 16), 256, 0, stream>>>(Hb, HbT);
    k_fused1<<<5000, 256, 0, stream>>>(X, W, att, expn, Yv);
    k_transFE<<<KPAD1 / 64, 256, 0, stream>>>(Yv, expn, VtT1);
    // pass 1: [4000 x 80] = HbT @ [Yv | expn | 0]
    k_mm<5><<<dim3(IPAD1 / 256, SPLITS1), 256, 0, stream>>>(HbT, HBT_W, N_EDGES, VtT1,
                                                            KPAD1, KPAD1 / SPLITS1, P, IPAD1);
    k_aggT<<<KPAD2 / 64, 256, 0, stream>>>(P, VtT2);
    // pass 2: [20000 x 64] = Hb @ agg
    k_mm<4><<<dim3(IPAD2 / 256, SPLITS2), 256, 0, stream>>>(Hb, HB_W, N_NODES, VtT2,
                                                            KPAD2, KPAD2 / SPLITS2, P, IPAD2);
    k_final4<<<1250, 256, 0, stream>>>(P, bias, out);
}

// Round 9
// 534.034 us; speedup vs baseline: 1.0574x; 1.0574x over previous
//
#include <hip/hip_runtime.h>
#include <math.h>

#define N_NODES 20000
#define N_EDGES 4000
#define IN_DIM 128
#define NUM_HEADS 8
#define ALPHA 0.2f

#define HB_W 64      // u64 words per Hb row (e-bits): 4096 bits
#define HBT_W 320    // u64 words per HbT row (n-bits): 20480 bits
#define KPAD1 20480
#define KPAD2 4096
#define IPAD1 4096   // 16 blocks x 256 rows
#define IPAD2 20224  // 79 blocks x 256 rows
#define SPLITS1 32   // 640 k each = 5 stages of 128 (R6 best-measured config)
#define SPLITS2 8    // 512 k each = 4 stages of 128

typedef float f32x4 __attribute__((ext_vector_type(4)));
typedef __bf16 bf16x8 __attribute__((ext_vector_type(8)));

// ---------- workspace layout (bytes) ----------
// Hb   : u64 [20000][64]   @ 0           10,240,000
// HbT  : u64 [4000][320]   @ 10,240,000  10,240,000
// VtT1 : bf16 [80][20480]  @ 20,480,000   3,276,800
// VtT2 : bf16 [64][4096]   @ 23,756,800     524,288
// expn : f32 [20000][8]    @ 24,281,088     640,000
// Yv   : f32 [20000][64]   @ 24,921,088   5,120,000
// P    : f32 partials      @ 30,041,088  41,943,040  (P1: 32x4096x80 / P2: 8x20224x64)

__device__ __forceinline__ unsigned short f2b(float f) {  // fp32 -> bf16 RNE
    unsigned u = __float_as_uint(f);
    return (unsigned short)((u + 0x7FFFu + ((u >> 16) & 1u)) >> 16);
}

// ================= Kernel A: pack (even blocks) || fused1 (odd blocks) =================
// Independent front-chain roots horizontally fused: pack's HBM-bound 320MB H read
// overlaps fused1's VALU-bound X@W (m114: VMEM-wave + VALU-wave co-schedule).
__global__ void __launch_bounds__(256) kA(const int* __restrict__ H,
                                          unsigned long long* __restrict__ Hb,
                                          const float* __restrict__ X,
                                          const float* __restrict__ W,
                                          const float* __restrict__ att,
                                          float* __restrict__ expn,
                                          float* __restrict__ Yv) {
    int role = blockIdx.x & 1;
    int bid = blockIdx.x >> 1;
    if (role == 0) {
        // ---- bitpack H: register shfl-OR tree; 2 loads in flight ----
        int wq = threadIdx.x >> 6;
        int lane = threadIdx.x & 63;
        int n = bid * 4 + wq;
        const int* hrow = H + (size_t)n * N_EDGES;
        unsigned long long* brow = Hb + (size_t)n * HB_W;
        int g = lane >> 4;
        int sh = 4 * (lane & 15);
        for (int it = 0; it < 16; it += 2) {
            int e0 = it * 256 + lane * 4;
            int e1 = e0 + 256;
            unsigned long long v0 = 0ull, v1 = 0ull;
            if (e0 < N_EDGES) {
                int4 v = *(const int4*)(hrow + e0);
                unsigned nb = (v.x > 0 ? 1u : 0u) | (v.y > 0 ? 2u : 0u) |
                              (v.z > 0 ? 4u : 0u) | (v.w > 0 ? 8u : 0u);
                v0 = (unsigned long long)nb << sh;
            }
            if (e1 < N_EDGES) {
                int4 v = *(const int4*)(hrow + e1);
                unsigned nb = (v.x > 0 ? 1u : 0u) | (v.y > 0 ? 2u : 0u) |
                              (v.z > 0 ? 4u : 0u) | (v.w > 0 ? 8u : 0u);
                v1 = (unsigned long long)nb << sh;
            }
            v0 |= __shfl_xor(v0, 1, 64);  v1 |= __shfl_xor(v1, 1, 64);
            v0 |= __shfl_xor(v0, 2, 64);  v1 |= __shfl_xor(v1, 2, 64);
            v0 |= __shfl_xor(v0, 4, 64);  v1 |= __shfl_xor(v1, 4, 64);
            v0 |= __shfl_xor(v0, 8, 64);  v1 |= __shfl_xor(v1, 8, 64);
            if ((lane & 15) == 0) {
                brow[it * 4 + g] = v0;
                brow[it * 4 + 4 + g] = v1;
            }
        }
    } else {
        // ---- Xh = X@W ; s = leaky_relu(Xh.a) ; e = exp(s) (max-shift cancels) ----
        int t = bid * 256 + threadIdx.x;
        int n = __builtin_amdgcn_readfirstlane(t >> 6);
        int d = t & 63;
        const float* x = X + (size_t)n * IN_DIM;
        float acc = 0.f;
#pragma unroll 8
        for (int k = 0; k < IN_DIM; k++) acc += x[k] * W[k * 64 + d];
        int h = d >> 3, j = d & 7;
        float av = att[h * 16 + j] + att[h * 16 + 8 + j];
        float v = acc * av;
        v += __shfl_xor(v, 1, 64);
        v += __shfl_xor(v, 2, 64);
        v += __shfl_xor(v, 4, 64);
        float s = (v >= 0.f) ? v : ALPHA * v;
        float e = expf(s);
        Yv[(size_t)n * 64 + d] = e * acc;
        if (j == 0) expn[(size_t)n * NUM_HEADS + h] = e;
    }
}

// ============ Kernel B: transFE (blocks 0..319) || transB (blocks 320..5327) ============
__global__ void __launch_bounds__(256) kB(const unsigned long long* __restrict__ Hb,
                                          unsigned long long* __restrict__ HbT,
                                          const float* __restrict__ Yv,
                                          const float* __restrict__ expn,
                                          unsigned short* __restrict__ VtT1) {
    __shared__ float tl[64][65];
    if (blockIdx.x < 320) {
        // ---- Yv + expn -> VtT1 bf16 [80][KPAD1] (rows 0-63 Yv^T, 64-71 expn^T, 72-79 zero)
        int t = threadIdx.x;
        int n0 = blockIdx.x * 64;
        int r = t >> 2, s4 = t & 3;
#pragma unroll
        for (int m = 0; m < 4; m++) {
            int cbase = s4 * 16 + m * 4;
            float4 v = make_float4(0.f, 0.f, 0.f, 0.f);
            if (n0 + r < N_NODES) v = *(const float4*)(Yv + (size_t)(n0 + r) * 64 + cbase);
            tl[r][cbase] = v.x; tl[r][cbase + 1] = v.y; tl[r][cbase + 2] = v.z; tl[r][cbase + 3] = v.w;
        }
        __syncthreads();
        int d = t >> 2;
        unsigned short buf[16];
#pragma unroll
        for (int j = 0; j < 16; j++) buf[j] = f2b(tl[s4 * 16 + j][d]);
        uint4* o = (uint4*)(VtT1 + (size_t)d * KPAD1 + n0 + s4 * 16);
        o[0] = *(uint4*)&buf[0];
        o[1] = *(uint4*)&buf[8];
        int nl = t & 63;
        int rw = t >> 6;
#pragma unroll
        for (int p = 0; p < 4; p++) {
            int row = 64 + rw * 4 + p;
            float v = 0.f;
            if (row < 72 && n0 + nl < N_NODES) v = expn[(size_t)(n0 + nl) * NUM_HEADS + (row - 64)];
            VtT1[(size_t)row * KPAD1 + n0 + nl] = f2b(v);
        }
    } else {
        // ---- ballot bit-transpose: Hb[n][e-word] -> HbT[e][n-word] ----
        int b = blockIdx.x - 320;       // 0..5007
        int bx = b % 313;               // n-block
        int by = b / 313;               // 0..15
        int wq = threadIdx.x >> 6;
        int lane = threadIdx.x & 63;
        int et = by * 4 + wq;
        if (et >= 63) return;
        int n0 = bx * 64;
        int n = n0 + lane;
        unsigned long long w = (n < N_NODES) ? Hb[(size_t)n * HB_W + et] : 0ull;
        unsigned long long out = 0ull;
#pragma unroll
        for (int c = 0; c < 64; c++) {
            unsigned long long bb = __ballot((w >> c) & 1ull);
            if (lane == c) out = bb;
        }
        int e = et * 64 + lane;
        if (e < N_EDGES) HbT[(size_t)e * HBT_W + bx] = out;
    }
}

__device__ __forceinline__ bf16x8 expand8(unsigned b) {
    union { uint4 u; bf16x8 v; } cv;
    cv.u.x = ((b & 1u)   ? 0x3F80u : 0u) | ((b & 2u)   ? 0x3F800000u : 0u);
    cv.u.y = ((b & 4u)   ? 0x3F80u : 0u) | ((b & 8u)   ? 0x3F800000u : 0u);
    cv.u.z = ((b & 16u)  ? 0x3F80u : 0u) | ((b & 32u)  ? 0x3F800000u : 0u);
    cv.u.w = ((b & 64u)  ? 0x3F80u : 0u) | ((b & 128u) ? 0x3F800000u : 0u);
    return cv.v;
}
__device__ __forceinline__ bf16x8 ldsread(const unsigned short* p) {
    union { uint4 u; bf16x8 v; } cv;
    cv.u = *(const uint4*)p;
    return cv.v;
}

// ---- bit-mask MFMA GEMM: C[I, NCT*16] = bits[I,K] @ V[K, NCT*16]
// Fragment-order LDS (conflict-free b128). Wave owns 4 row-tiles; block = 256 rows;
// K-split over grid.y -> disjoint fp32 partials (no atomics).
template <int NCT>
__global__ void __launch_bounds__(256) k_mm(const unsigned long long* __restrict__ bits,
                                            int stride, int I,
                                            const unsigned short* __restrict__ Vg,
                                            int Kpad, int kPerSplit,
                                            float* __restrict__ P, int Ipad) {
    __shared__ __align__(16) unsigned short VldsF[NCT * 4 * 64 * 8];
    const int t = threadIdx.x;
    const int l = t & 63;
    const int w = t >> 6;
    const int q = l >> 4;
    const int cl = l & 15;
    const int rowbase = blockIdx.x * 256 + w * 64;
    const int k0 = blockIdx.y * kPerSplit;
    const int nstages = kPerSplit >> 7;

    const unsigned long long* bp[4];
#pragma unroll
    for (int rt = 0; rt < 4; rt++) {
        int r = rowbase + rt * 16 + cl;
        if (r >= I) r = I - 1;
        bp[rt] = bits + (size_t)r * stride;
    }

    f32x4 acc[4][NCT];
#pragma unroll
    for (int rt = 0; rt < 4; rt++)
#pragma unroll
        for (int c = 0; c < NCT; c++) acc[rt][c] = (f32x4){0.f, 0.f, 0.f, 0.f};

    for (int st = 0; st < nstages; st++) {
        int kc = k0 + st * 128;
        __syncthreads();
#pragma unroll
        for (int c = 0; c < NCT; c++) {
            uint4 val = *(const uint4*)(Vg + (size_t)(c * 16 + cl) * Kpad + kc + (w * 4 + q) * 8);
            *(uint4*)&VldsF[(((c * 4 + w) * 64) + l) * 8] = val;
        }
        ulonglong2 wb[4];
#pragma unroll
        for (int rt = 0; rt < 4; rt++) wb[rt] = *(const ulonglong2*)(bp[rt] + (kc >> 6));
        __syncthreads();
#pragma unroll
        for (int kf = 0; kf < 4; kf++) {
            bf16x8 a[4];
#pragma unroll
            for (int rt = 0; rt < 4; rt++) {
                unsigned long long wsel = (kf < 2) ? wb[rt].x : wb[rt].y;
                unsigned byte = (unsigned)(wsel >> ((kf & 1) * 32 + q * 8)) & 0xFFu;
                a[rt] = expand8(byte);
            }
#pragma unroll
            for (int c = 0; c < NCT; c++) {
                bf16x8 bv = ldsread(&VldsF[(((c * 4 + kf) * 64) + l) * 8]);
#pragma unroll
                for (int rt = 0; rt < 4; rt++)
                    acc[rt][c] = __builtin_amdgcn_mfma_f32_16x16x32_bf16(a[rt], bv, acc[rt][c], 0, 0, 0);
            }
        }
    }

    size_t base = (size_t)blockIdx.y * Ipad;
#pragma unroll
    for (int rt = 0; rt < 4; rt++)
#pragma unroll
        for (int c = 0; c < NCT; c++)
#pragma unroll
            for (int r = 0; r < 4; r++)
                P[(base + rowbase + rt * 16 + q * 4 + r) * (NCT * 16) + c * 16 + cl] = acc[rt][c][r];
}

// ---- reduce pass-1 partials, divide, write VtT2 bf16 transposed ----
__global__ void __launch_bounds__(256) k_aggT(const float* __restrict__ P1,
                                              unsigned short* __restrict__ VtT2) {
    __shared__ float tl[64][65];
    int t = threadIdx.x;
    int e0 = blockIdx.x * 64;
    int el = t >> 2, s4 = t & 3;
    int e = e0 + el;
    float num[16];
#pragma unroll
    for (int j = 0; j < 16; j++) num[j] = 0.f;
    float den0 = 0.f, den1 = 0.f;
    for (int sp = 0; sp < SPLITS1; sp++) {
        const float* row = P1 + ((size_t)sp * IPAD1 + e) * 80;
        const float4* r4 = (const float4*)(row + s4 * 16);
        float4 a = r4[0], b = r4[1], c = r4[2], d = r4[3];
        num[0] += a.x;  num[1] += a.y;  num[2] += a.z;  num[3] += a.w;
        num[4] += b.x;  num[5] += b.y;  num[6] += b.z;  num[7] += b.w;
        num[8] += c.x;  num[9] += c.y;  num[10] += c.z; num[11] += c.w;
        num[12] += d.x; num[13] += d.y; num[14] += d.z; num[15] += d.w;
        float2 dn = *(const float2*)(row + 64 + s4 * 2);
        den0 += dn.x; den1 += dn.y;
    }
#pragma unroll
    for (int j = 0; j < 16; j++) {
        float den = (j < 8) ? den0 : den1;
        float v = (e < N_EDGES && den > 0.f) ? num[j] / den : 0.f;
        tl[el][s4 * 16 + j] = v;
    }
    __syncthreads();
    int d = t >> 2;
    unsigned short buf[16];
#pragma unroll
    for (int j = 0; j < 16; j++) buf[j] = f2b(tl[s4 * 16 + j][d]);
    uint4* o = (uint4*)(VtT2 + (size_t)d * KPAD2 + e0 + s4 * 16);
    o[0] = *(uint4*)&buf[0];
    o[1] = *(uint4*)&buf[8];
}

// ---- out = sum of pass-2 partials + bias (float4) ----
__global__ void __launch_bounds__(256) k_final4(const float* __restrict__ P2,
                                                const float* __restrict__ bias,
                                                float* __restrict__ out) {
    int t = blockIdx.x * blockDim.x + threadIdx.x;   // 320000 threads
    int n = t >> 4, c4 = t & 15;
    float4 v = *(const float4*)(bias + c4 * 4);
#pragma unroll
    for (int sp = 0; sp < SPLITS2; sp++) {
        float4 p = *(const float4*)(P2 + ((size_t)sp * IPAD2 + n) * 64 + c4 * 4);
        v.x += p.x; v.y += p.y; v.z += p.z; v.w += p.w;
    }
    *(float4*)(out + (size_t)n * 64 + c4 * 4) = v;
}

extern "C" void kernel_launch(void* const* d_in, const int* in_sizes, int n_in,
                              void* d_out, int out_size, void* d_ws, size_t ws_size,
                              hipStream_t stream) {
    const float* X = (const float*)d_in[0];
    const int* H = (const int*)d_in[1];
    const float* W = (const float*)d_in[2];
    const float* att = (const float*)d_in[3];
    const float* bias = (const float*)d_in[4];
    float* out = (float*)d_out;

    char* ws = (char*)d_ws;
    unsigned long long* Hb  = (unsigned long long*)(ws + 0);
    unsigned long long* HbT = (unsigned long long*)(ws + 10240000);
    unsigned short* VtT1 = (unsigned short*)(ws + 20480000);
    unsigned short* VtT2 = (unsigned short*)(ws + 23756800);
    float* expn = (float*)(ws + 24281088);
    float* Yv   = (float*)(ws + 24921088);
    float* P    = (float*)(ws + 30041088);

    // A: pack || fused1   (independent roots, block-parity interleaved)
    kA<<<10000, 256, 0, stream>>>(H, Hb, X, W, att, expn, Yv);
    // B: transFE || transB
    kB<<<5328, 256, 0, stream>>>(Hb, HbT, Yv, expn, VtT1);
    // pass 1: [4000 x 80] = HbT @ [Yv | expn | 0]
    k_mm<5><<<dim3(IPAD1 / 256, SPLITS1), 256, 0, stream>>>(HbT, HBT_W, N_EDGES, VtT1,
                                                            KPAD1, KPAD1 / SPLITS1, P, IPAD1);
    k_aggT<<<KPAD2 / 64, 256, 0, stream>>>(P, VtT2);
    // pass 2: [20000 x 64] = Hb @ agg
    k_mm<4><<<dim3(IPAD2 / 256, SPLITS2), 256, 0, stream>>>(Hb, HB_W, N_NODES, VtT2,
                                                            KPAD2, KPAD2 / SPLITS2, P, IPAD2);
    k_final4<<<1250, 256, 0, stream>>>(P, bias, out);
}